// Round 12
// baseline (1463.958 us; speedup 1.0000x reference)
//
#include <hip/hip_runtime.h>
#include <hip/hip_bf16.h>
#include <stdint.h>

// B=16, C=1024, D=H=W=8 -> N=512 tokens, 27 taps
#define BATCH 16
#define CCH   1024
#define NTOK  512
#define NKT   432   // K-tiles: 27 taps * (1024/64)

typedef _Float16 f16_t;
typedef f16_t f16x8 __attribute__((ext_vector_type(8)));
typedef f16_t f16x4 __attribute__((ext_vector_type(4)));
typedef float f32x4 __attribute__((ext_vector_type(4)));

#define GAS __attribute__((address_space(1)))
#define LAS __attribute__((address_space(3)))

__device__ __forceinline__ void gload_lds16(const void* g, void* l) {
  __builtin_amdgcn_global_load_lds((const GAS uint32_t*)g, (LAS uint32_t*)l, 16, 0, 0);
}

// ---------------- cast + transpose: [B][C][N] f32 -> [B][N][C] f16 -----------
__global__ __launch_bounds__(256) void cast_transpose_kernel(
    const float* __restrict__ src, f16_t* __restrict__ dst) {
  __shared__ float tile[64][65];
  const int b  = blockIdx.z;
  const int c0 = blockIdx.y * 64;
  const int n0 = blockIdx.x * 64;
  const int col  = threadIdx.x & 63;
  const int row4 = threadIdx.x >> 6;
  const float* s = src + ((size_t)b * CCH + c0) * NTOK + n0;
#pragma unroll
  for (int r = 0; r < 64; r += 4)
    tile[r + row4][col] = s[(size_t)(r + row4) * NTOK + col];
  __syncthreads();
  f16_t* d = dst + ((size_t)b * NTOK + n0) * CCH + c0;
#pragma unroll
  for (int r = 0; r < 64; r += 4)
    d[(size_t)(r + row4) * CCH + col] = (f16_t)tile[col][r + row4];
}

// -------- weight transpose: [O][I][27] f32 -> rows o_base+o of [27][Mtot][1024]
__global__ __launch_bounds__(256) void wtrans_kernel(
    const float* __restrict__ w, f16_t* __restrict__ wt, const int o_base,
    const int Mtot) {
  __shared__ float buf[64 * 27];
  const int o  = blockIdx.x;
  const int i0 = blockIdx.y * 64;
  const float* s = w + (size_t)o * (CCH * 27) + (size_t)i0 * 27;
  for (int idx = threadIdx.x; idx < 64 * 27; idx += 256) buf[idx] = s[idx];
  __syncthreads();
  for (int idx = threadIdx.x; idx < 64 * 27; idx += 256) {
    const int t = idx >> 6;
    const int i = idx & 63;
    wt[((size_t)t * Mtot + o_base + o) * 1024 + i0 + i] = (f16_t)buf[i * 27 + t];
  }
}

// ================= conv K+V fused: M=2048, tile 256x256, BK=64 ===============
// 256 blocks, 8 waves (2M x 4N), wave 128x64, acc 8x4; 4-half 32KB ring.
// m201-style 4-phase/K-tile: each phase {ds_read subtile; 2 stage issues;
// barrier; setprio+16 MFMA; [vmcnt(8) at ph1/ph3] barrier}. Counted vmcnt
// keeps 8 loads in flight across every barrier. Src-side slot swizzle.
__global__ __launch_bounds__(512, 2) void conv_kv_kernel(
    const f16_t* __restrict__ y_t, const f16_t* __restrict__ wkv,
    const float* __restrict__ bkv, f16_t* __restrict__ kb,
    f16_t* __restrict__ vb, const char* __restrict__ zp) {
  __shared__ char lds[131072];
  const int tid  = threadIdx.x;
  const int lane = tid & 63;
  const int wid  = tid >> 6;
  const int wr = wid >> 2, wc = wid & 3;   // 2M x 4N

  const int id = blockIdx.x;               // 256 blocks
  const int panel  = id & 7;               // 0..7 (0-3 = k, 4-7 = v)
  const int n_tile = id >> 3;              // 0..31
  const int m0  = panel * 256;             // row in 2048
  const int bn0 = n_tile * 256;
  const int b   = bn0 >> 9;
  const int n0  = bn0 & 511;
  const char* src_c = (const char*)y_t + (size_t)b * NTOK * 2048;
  const char* w_c   = (const char*)wkv;

  const int slotsrc16 = (((tid & 3) ^ ((tid >> 3) & 3)) << 4);
  const int t16 = tid << 4;
  const int r0t = tid >> 2;                // 0..127
  const size_t arow0 = (size_t)(m0 + r0t) * 2048 + slotsrc16;

  int cur_tap = -1;
  const char* bp0 = zp;
  const char* bp1 = zp;

  const int fr = lane & 15;
  const int rdbase = fr * 64 + (((lane >> 4) ^ ((fr >> 1) & 3)) << 4);

  f32x4 acc[8][4] = {};

  auto upd_tap = [&](int tap) {
    cur_tap = tap;
    const int kd = tap / 9, rem = tap % 9, kh3 = rem / 3, kw3 = rem % 3;
#pragma unroll
    for (int l = 0; l < 2; ++l) {
      const int n = n0 + r0t + l * 128;
      const int d = (n >> 6) + kd - 1;
      const int h = ((n >> 3) & 7) + kh3 - 1;
      const int w = (n & 7) + kw3 - 1;
      const bool ok = ((unsigned)d < 8u) & ((unsigned)h < 8u) & ((unsigned)w < 8u);
      const int nsrc = (d << 6) + (h << 3) + w;
      const char* p = ok ? src_c + (size_t)nsrc * 2048 + slotsrc16 : zp;
      if (l == 0) bp0 = p; else bp1 = p;
    }
  };
  // A-pair (2 issues) of kh-half of K-tile tt -> ring region `reg`
  auto stage_pairA = [&](int tt, int kh, int reg) {
    const int te = (tt < NKT) ? tt : tt - 2;   // parity-preserving tail remap
    const int tap = te >> 4, kt = te & 15;
    if (tap != cur_tap) upd_tap(tap);
    const size_t gA = (size_t)tap * (2048u * 2048u) + (size_t)(kt * 128 + kh * 64);
    char* La = lds + reg;
    gload_lds16(w_c + gA + arow0,                      La + t16);
    gload_lds16(w_c + gA + arow0 + (size_t)128 * 2048, La + 8192 + t16);
  };
  // B-pair (2 issues)
  auto stage_pairB = [&](int tt, int kh, int reg) {
    const int te = (tt < NKT) ? tt : tt - 2;
    const int tap = te >> 4, kt = te & 15;
    if (tap != cur_tap) upd_tap(tap);
    const int ko = kt * 128 + kh * 64;
    char* La = lds + reg;
    gload_lds16(bp0 + ko, La + 16384 + t16);
    gload_lds16(bp1 + ko, La + 24576 + t16);
  };

#define MFMA16G(IOFF, AV, BV)                                                  \
  _Pragma("unroll") for (int i = 0; i < 4; ++i) {                              \
    _Pragma("unroll") for (int j = 0; j < 4; ++j)                              \
        acc[IOFF + i][j] = __builtin_amdgcn_mfma_f32_16x16x32_f16(             \
            AV[i], BV[j], acc[IOFF + i][j], 0, 0, 0);                          \
  }
#define BAR()    asm volatile("s_barrier" ::: "memory")
#define BARVM8() asm volatile("s_waitcnt vmcnt(8)\n\ts_barrier" ::: "memory")

  // prologue: (0,kh0)(0,kh1)(1,kh0) = 12 issues; wait half0 (keep 8 in flight)
  stage_pairA(0, 0, 0);      stage_pairB(0, 0, 0);
  stage_pairA(0, 1, 32768);  stage_pairB(0, 1, 32768);
  stage_pairA(1, 0, 65536);  stage_pairB(1, 0, 65536);
  BARVM8();

#pragma unroll 1
  for (int t = 0; t < NKT; ++t) {
    const int rb  = (t & 1) << 16;
    const int rb1 = (((t + 1) & 1) << 16) + 32768;  // (t+1, kh1) region
    const int rb2 = (t & 1) << 16;                  // (t+2, kh0) region
    const char* sA0 = lds + rb + wr * 8192 + rdbase;
    const char* sB0 = lds + rb + 16384 + wc * 4096 + rdbase;
    const char* sA1 = lds + rb + 32768 + wr * 8192 + rdbase;
    const char* sB1 = lds + rb + 32768 + 16384 + wc * 4096 + rdbase;
    f16x8 av[4], bv[4];
    // ---- phase 0: kh0, rows 0-3 (+ bv0 read); stage (t+1,kh1) A-pair
#pragma unroll
    for (int j = 0; j < 4; ++j) bv[j] = *(const f16x8*)(sB0 + j * 1024);
#pragma unroll
    for (int i = 0; i < 4; ++i) av[i] = *(const f16x8*)(sA0 + i * 1024);
    stage_pairA(t + 1, 1, rb1);
    BAR();
    __builtin_amdgcn_s_setprio(1);
    MFMA16G(0, av, bv)
    __builtin_amdgcn_s_setprio(0);
    BAR();
    // ---- phase 1: kh0, rows 4-7; stage (t+1,kh1) B-pair; counted vmcnt
#pragma unroll
    for (int i = 0; i < 4; ++i) av[i] = *(const f16x8*)(sA0 + (4 + i) * 1024);
    stage_pairB(t + 1, 1, rb1);
    BAR();
    __builtin_amdgcn_s_setprio(1);
    MFMA16G(4, av, bv)
    __builtin_amdgcn_s_setprio(0);
    BARVM8();
    // ---- phase 2: kh1, rows 0-3 (+ bv1 read); stage (t+2,kh0) A-pair
#pragma unroll
    for (int j = 0; j < 4; ++j) bv[j] = *(const f16x8*)(sB1 + j * 1024);
#pragma unroll
    for (int i = 0; i < 4; ++i) av[i] = *(const f16x8*)(sA1 + i * 1024);
    stage_pairA(t + 2, 0, rb2);
    BAR();
    __builtin_amdgcn_s_setprio(1);
    MFMA16G(0, av, bv)
    __builtin_amdgcn_s_setprio(0);
    BAR();
    // ---- phase 3: kh1, rows 4-7; stage (t+2,kh0) B-pair; counted vmcnt
#pragma unroll
    for (int i = 0; i < 4; ++i) av[i] = *(const f16x8*)(sA1 + (4 + i) * 1024);
    stage_pairB(t + 2, 0, rb2);
    BAR();
    __builtin_amdgcn_s_setprio(1);
    MFMA16G(4, av, bv)
    __builtin_amdgcn_s_setprio(0);
    BARVM8();
  }
#undef MFMA16G
#undef BAR
#undef BARVM8

  // epilogue: C col=lane&15 -> token, row=(lane>>4)*4+reg -> channel
  const int rq = (lane >> 4) << 2;
  const bool is_k = panel < 4;
#pragma unroll
  for (int i = 0; i < 8; ++i) {
    const int c = m0 + wr * 128 + i * 16 + rq;       // 0..2047
    const float4 bs = *(const float4*)&bkv[c];
    if (is_k) {
#pragma unroll
      for (int j = 0; j < 4; ++j) {
        const int n = n0 + wc * 64 + j * 16 + fr;
        f16x4 pk;
        pk[0] = (f16_t)(acc[i][j][0] + bs.x);
        pk[1] = (f16_t)(acc[i][j][1] + bs.y);
        pk[2] = (f16_t)(acc[i][j][2] + bs.z);
        pk[3] = (f16_t)(acc[i][j][3] + bs.w);
        *(f16x4*)(kb + ((size_t)(b * NTOK + n)) * CCH + c) = pk;
      }
    } else {
      const int cc = c - 1024;
      const float bbv[4] = {bs.x, bs.y, bs.z, bs.w};
#pragma unroll
      for (int reg = 0; reg < 4; ++reg) {
        f16_t* dst = vb + ((size_t)b * CCH + cc + reg) * NTOK;
#pragma unroll
        for (int j = 0; j < 4; ++j) {
          const int n = n0 + wc * 64 + j * 16 + fr;
          dst[n] = (f16_t)(acc[i][j][reg] + bbv[reg]);
        }
      }
    }
  }
}

// ================= conv Q: M=1024, tile 256x128, BK=64 (R6 verbatim) =========
__global__ __launch_bounds__(512, 2) void conv_q_kernel(
    const f16_t* __restrict__ x_t, const f16_t* __restrict__ wqt,
    const float* __restrict__ bq, f16_t* __restrict__ qb,
    const char* __restrict__ zp) {
  __shared__ char lds[98304];
  const int tid  = threadIdx.x;
  const int lane = tid & 63;
  const int wid  = tid >> 6;
  const int wr = wid >> 1, wc = wid & 1;   // 4M x 2N

  const int id = blockIdx.x;               // 256 blocks
  const int panel  = id & 3;               // 0..3
  const int n_tile = id >> 2;              // 0..63
  const int m0  = panel * 256;
  const int bn0 = n_tile * 128;
  const int b   = bn0 >> 9;
  const int n0  = bn0 & 511;
  const char* src_c = (const char*)x_t + (size_t)b * NTOK * 2048;
  const char* w_c   = (const char*)wqt;

  const int slotsrc16 = (((tid & 3) ^ ((tid >> 3) & 3)) << 4);
  const int t16 = tid << 4;
  const int r0  = tid >> 2;
  const size_t arow0 = (size_t)(m0 + r0) * 2048 + slotsrc16;

  int cur_tap = -1;
  const char* bp0 = zp;

  const int fr = lane & 15;
  const int rdbase = fr * 64 + (((lane >> 4) ^ ((fr >> 1) & 3)) << 4);

  f32x4 acc[4][4] = {};

  auto upd_tap = [&](int tap) {
    cur_tap = tap;
    const int kd = tap / 9, rem = tap % 9, kh = rem / 3, kw = rem % 3;
    const int n = n0 + r0;
    const int d = (n >> 6) + kd - 1;
    const int h = ((n >> 3) & 7) + kh - 1;
    const int w = (n & 7) + kw - 1;
    const bool ok = ((unsigned)d < 8u) & ((unsigned)h < 8u) & ((unsigned)w < 8u);
    const int nsrc = (d << 6) + (h << 3) + w;
    bp0 = ok ? src_c + (size_t)nsrc * 2048 + slotsrc16 : zp;
  };
  auto stage_half = [&](int tt, int kh, int reg) {  // 3 loads
    const int te = (tt < NKT) ? tt : tt - 2;
    const int tap = te >> 4, kt = te & 15;
    if (tap != cur_tap) upd_tap(tap);
    const size_t gA = (size_t)tap * (1024u * 2048u) + (size_t)(kt * 128 + kh * 64);
    char* La = lds + reg;
    gload_lds16(w_c + gA + arow0,                      La + t16);
    gload_lds16(w_c + gA + arow0 + (size_t)128 * 2048, La + 8192 + t16);
    gload_lds16(bp0 + kt * 128 + kh * 64,              La + 16384 + t16);
  };

#define MFMA16Q(AV, BV)                                                        \
  _Pragma("unroll") for (int i = 0; i < 4; ++i) {                              \
    _Pragma("unroll") for (int j = 0; j < 4; ++j)                              \
        acc[i][j] = __builtin_amdgcn_mfma_f32_16x16x32_f16(                    \
            AV[i], BV[j], acc[i][j], 0, 0, 0);                                 \
  }

  stage_half(0, 0, 0);
  stage_half(0, 1, 24576);
  stage_half(1, 0, 49152);
  asm volatile("s_waitcnt vmcnt(6)\n\ts_barrier" ::: "memory");

#pragma unroll 1
  for (int t = 0; t < NKT; ++t) {
    const int rb = (t & 1) * 49152;               // region: tile t, kh0
    {
      const char* sA = lds + rb + wr * 4096 + rdbase;
      const char* sB = lds + rb + 16384 + wc * 4096 + rdbase;
      f16x8 av[4], bv[4];
#pragma unroll
      for (int j = 0; j < 4; ++j) bv[j] = *(const f16x8*)(sB + j * 1024);
#pragma unroll
      for (int i = 0; i < 4; ++i) av[i] = *(const f16x8*)(sA + i * 1024);
      stage_half(t + 1, 1, ((t + 1) & 1) * 49152 + 24576);
      __builtin_amdgcn_s_setprio(1);
      MFMA16Q(av, bv)
      __builtin_amdgcn_s_setprio(0);
      asm volatile("s_waitcnt vmcnt(6)\n\ts_barrier" ::: "memory");
    }
    {
      const char* sA = lds + rb + 24576 + wr * 4096 + rdbase;
      const char* sB = lds + rb + 24576 + 16384 + wc * 4096 + rdbase;
      f16x8 av[4], bv[4];
#pragma unroll
      for (int j = 0; j < 4; ++j) bv[j] = *(const f16x8*)(sB + j * 1024);
#pragma unroll
      for (int i = 0; i < 4; ++i) av[i] = *(const f16x8*)(sA + i * 1024);
      stage_half(t + 2, 0, (t & 1) * 49152);
      __builtin_amdgcn_s_setprio(1);
      MFMA16Q(av, bv)
      __builtin_amdgcn_s_setprio(0);
      asm volatile("s_waitcnt vmcnt(6)\n\ts_barrier" ::: "memory");
    }
  }
#undef MFMA16Q

  const int rq = (lane >> 4) << 2;
#pragma unroll
  for (int i = 0; i < 4; ++i) {
    const int c = m0 + wr * 64 + i * 16 + rq;        // 0..1023
    const float4 bs = *(const float4*)&bq[c];
#pragma unroll
    for (int j = 0; j < 4; ++j) {
      const int n = n0 + wc * 64 + j * 16 + fr;
      f16x4 pk;
      pk[0] = (f16_t)(acc[i][j][0] + bs.x);
      pk[1] = (f16_t)(acc[i][j][1] + bs.y);
      pk[2] = (f16_t)(acc[i][j][2] + bs.z);
      pk[3] = (f16_t)(acc[i][j][3] + bs.w);
      *(f16x4*)(qb + ((size_t)(b * NTOK + n)) * CCH + c) = pk;
    }
  }
}

// ---------------- generic gemm_bt for attention: C = A * Bt^T (+resid) -------
__global__ __launch_bounds__(256) void attn_gemm_kernel(
    const f16_t* __restrict__ A, const f16_t* __restrict__ Bt,
    float* __restrict__ Cout, const float* __restrict__ resid,
    const int Kdim, const int ldc,
    const size_t strideA, const size_t strideB, const size_t strideC) {
  __shared__ f16_t As[128 * 64];
  __shared__ f16_t Bs[128 * 64];
  char* As_c = (char*)As;
  char* Bs_c = (char*)Bs;

  const int tid  = threadIdx.x;
  const int lane = tid & 63;
  const int wave = tid >> 6;
  const int wr = wave >> 1, wc = wave & 1;
  const int bz = blockIdx.z;
  const int m0 = blockIdx.y * 128;
  const int n0 = blockIdx.x * 128;

  const f16_t* Ab = A + (size_t)bz * strideA;
  const f16_t* Bb = Bt + (size_t)bz * strideB;

  const int rowb = tid >> 3;
  const int colb = (tid & 7) * 16;

  const char* ap[4];
  const char* bp[4];
#pragma unroll
  for (int r = 0; r < 4; ++r) {
    const int row = r * 32 + rowb;
    ap[r] = (const char*)(Ab + (size_t)(m0 + row) * Kdim) + colb;
    bp[r] = (const char*)(Bb + (size_t)(n0 + row) * Kdim) + colb;
  }

  f32x4 acc[4][4] = {};
  const int fr = lane & 15;
  const int fk = (lane >> 4) << 3;

  for (int k0 = 0; k0 < Kdim; k0 += 64) {
#pragma unroll
    for (int r = 0; r < 4; ++r)
      gload_lds16(ap[r], As_c + r * 4096 + wave * 1024);
#pragma unroll
    for (int r = 0; r < 4; ++r)
      gload_lds16(bp[r], Bs_c + r * 4096 + wave * 1024);
#pragma unroll
    for (int r = 0; r < 4; ++r) { ap[r] += 128; bp[r] += 128; }
    __syncthreads();
#pragma unroll
    for (int ks = 0; ks < 2; ++ks) {
      const int kc = ks * 32 + fk;
      f16x8 av[4], bv[4];
#pragma unroll
      for (int i = 0; i < 4; ++i)
        av[i] = *(const f16x8*)&As[(wr * 64 + i * 16 + fr) * 64 + kc];
#pragma unroll
      for (int i = 0; i < 4; ++i)
        bv[i] = *(const f16x8*)&Bs[(wc * 64 + i * 16 + fr) * 64 + kc];
#pragma unroll
      for (int i = 0; i < 4; ++i)
#pragma unroll
        for (int j = 0; j < 4; ++j)
          acc[i][j] = __builtin_amdgcn_mfma_f32_16x16x32_f16(av[i], bv[j], acc[i][j], 0, 0, 0);
    }
    __syncthreads();
  }

  const int mo = m0 + wr * 64 + ((lane >> 4) << 2);
  const int nn = n0 + wc * 64 + (lane & 15);
  float* Cb = Cout + (size_t)bz * strideC;
  const float* Rb = resid ? resid + (size_t)bz * strideC : nullptr;
#pragma unroll
  for (int i = 0; i < 4; ++i) {
#pragma unroll
    for (int j = 0; j < 4; ++j) {
      const int n = nn + j * 16;
#pragma unroll
      for (int reg = 0; reg < 4; ++reg) {
        const int m = mo + i * 16 + reg;
        float v = acc[i][j][reg];
        if (Rb) v += Rb[(size_t)m * ldc + n];
        Cb[(size_t)m * ldc + n] = v;
      }
    }
  }
}

// ---------------- row softmax: S fp32 [rows][512] -> P f16 -------------------
__global__ __launch_bounds__(256) void softmax_kernel(
    const float* __restrict__ S, f16_t* __restrict__ P) {
  const int row  = blockIdx.x * 4 + (threadIdx.x >> 6);
  const int lane = threadIdx.x & 63;
  const float* s = S + (size_t)row * 512;
  const float4 v0 = ((const float4*)s)[lane];
  const float4 v1 = ((const float4*)s)[64 + lane];
  float m = fmaxf(fmaxf(fmaxf(v0.x, v0.y), fmaxf(v0.z, v0.w)),
                  fmaxf(fmaxf(v1.x, v1.y), fmaxf(v1.z, v1.w)));
#pragma unroll
  for (int o = 32; o; o >>= 1) m = fmaxf(m, __shfl_xor(m, o, 64));
  float e[8];
  e[0] = __expf(v0.x - m); e[1] = __expf(v0.y - m);
  e[2] = __expf(v0.z - m); e[3] = __expf(v0.w - m);
  e[4] = __expf(v1.x - m); e[5] = __expf(v1.y - m);
  e[6] = __expf(v1.z - m); e[7] = __expf(v1.w - m);
  float sum = ((e[0] + e[1]) + (e[2] + e[3])) + ((e[4] + e[5]) + (e[6] + e[7]));
#pragma unroll
  for (int o = 32; o; o >>= 1) sum += __shfl_xor(sum, o, 64);
  const float r = 1.0f / sum;
  f16_t* p = P + (size_t)row * 512;
  f16x4 o0, o1;
  o0[0] = (f16_t)(e[0] * r); o0[1] = (f16_t)(e[1] * r);
  o0[2] = (f16_t)(e[2] * r); o0[3] = (f16_t)(e[3] * r);
  o1[0] = (f16_t)(e[4] * r); o1[1] = (f16_t)(e[5] * r);
  o1[2] = (f16_t)(e[6] * r); o1[3] = (f16_t)(e[7] * r);
  ((f16x4*)p)[lane] = o0;
  ((f16x4*)p)[64 + lane] = o1;
}

// -----------------------------------------------------------------------------
extern "C" void kernel_launch(void* const* d_in, const int* in_sizes, int n_in,
                              void* d_out, int out_size, void* d_ws, size_t ws_size,
                              hipStream_t stream) {
  (void)in_sizes; (void)n_in; (void)out_size;
  const float* x  = (const float*)d_in[0];
  const float* y  = (const float*)d_in[1];
  const float* wq = (const float*)d_in[2];
  const float* bq = (const float*)d_in[3];
  const float* wk = (const float*)d_in[4];
  const float* bk = (const float*)d_in[5];
  const float* wv = (const float*)d_in[6];
  const float* bv = (const float*)d_in[7];

  char* ws = (char*)d_ws;
  size_t off = 0;
  auto alloc = [&](size_t bytes) {
    void* p = ws + off;
    off = (off + bytes + 255) & ~(size_t)255;
    return p;
  };
  const size_t act_b = (size_t)BATCH * NTOK * CCH * 2;  // 16 MB
  f16_t* x_t    = (f16_t*)alloc(act_b);
  f16_t* y_t    = (f16_t*)alloc(act_b);
  f16_t* wkv    = (f16_t*)alloc((size_t)27 * 2048 * 1024 * 2);   // 113 MB
  f16_t* wqt    = (f16_t*)alloc((size_t)27 * 1024 * 1024 * 2);   //  57 MB
  float* bkv    = (float*)alloc(2048 * 4);
  f16_t* qb     = (f16_t*)alloc(act_b);
  f16_t* kb     = (f16_t*)alloc(act_b);
  f16_t* vb     = (f16_t*)alloc(act_b);
  float* scores = (float*)alloc((size_t)BATCH * 512 * 512 * 4);  // 16 MB
  f16_t* Pb     = (f16_t*)alloc((size_t)BATCH * 512 * 512 * 2);  //  8 MB
  char*  zerop  = (char*)alloc(4096);
  if (off > ws_size) return;

  const dim3 blk(256);
  hipMemsetAsync(zerop, 0, 4096, stream);
  cast_transpose_kernel<<<dim3(8, 16, 16), blk, 0, stream>>>(x, x_t);
  cast_transpose_kernel<<<dim3(8, 16, 16), blk, 0, stream>>>(y, y_t);

  wtrans_kernel<<<dim3(1024, 16), blk, 0, stream>>>(wk, wkv, 0, 2048);
  wtrans_kernel<<<dim3(1024, 16), blk, 0, stream>>>(wv, wkv, 1024, 2048);
  wtrans_kernel<<<dim3(1024, 16), blk, 0, stream>>>(wq, wqt, 0, 1024);
  hipMemcpyAsync(bkv,        bk, 1024 * 4, hipMemcpyDeviceToDevice, stream);
  hipMemcpyAsync(bkv + 1024, bv, 1024 * 4, hipMemcpyDeviceToDevice, stream);

  conv_kv_kernel<<<dim3(256), dim3(512), 0, stream>>>(y_t, wkv, bkv, kb, vb, zerop);
  conv_q_kernel<<<dim3(256), dim3(512), 0, stream>>>(x_t, wqt, bq, qb, zerop);

  // scores[b][n][m] = sum_c q[b][n][c] * k[b][m][c]
  attn_gemm_kernel<<<dim3(4, 4, 16), blk, 0, stream>>>(
      qb, kb, scores, nullptr, 1024, 512,
      (size_t)512 * 1024, (size_t)512 * 1024, (size_t)512 * 512);
  softmax_kernel<<<dim3(BATCH * 512 / 4), blk, 0, stream>>>(scores, Pb);
  // out[b][c][n] = sum_m v[b][c][m] * P[b][n][m] + x[b][c][n]
  attn_gemm_kernel<<<dim3(4, 8, 16), blk, 0, stream>>>(
      vb, Pb, (float*)d_out, x, 512, 512,
      (size_t)1024 * 512, (size_t)512 * 512, (size_t)1024 * 512);
}

// Round 13
// 1442.635 us; speedup vs baseline: 1.0148x; 1.0148x over previous
//
#include <hip/hip_runtime.h>
#include <hip/hip_bf16.h>
#include <stdint.h>

// B=16, C=1024, D=H=W=8 -> N=512 tokens, 27 taps
#define BATCH 16
#define CCH   1024
#define NTOK  512
#define NKT   432   // K-tiles: 27 taps * (1024/64)

typedef _Float16 f16_t;
typedef f16_t f16x8 __attribute__((ext_vector_type(8)));
typedef f16_t f16x4 __attribute__((ext_vector_type(4)));
typedef float f32x4 __attribute__((ext_vector_type(4)));

#define GAS __attribute__((address_space(1)))
#define LAS __attribute__((address_space(3)))

__device__ __forceinline__ void gload_lds16(const void* g, void* l) {
  __builtin_amdgcn_global_load_lds((const GAS uint32_t*)g, (LAS uint32_t*)l, 16, 0, 0);
}

// ---------------- cast + transpose: [B][C][N] f32 -> [B][N][C] f16 -----------
__global__ __launch_bounds__(256) void cast_transpose_kernel(
    const float* __restrict__ src, f16_t* __restrict__ dst) {
  __shared__ float tile[64][65];
  const int b  = blockIdx.z;
  const int c0 = blockIdx.y * 64;
  const int n0 = blockIdx.x * 64;
  const int col  = threadIdx.x & 63;
  const int row4 = threadIdx.x >> 6;
  const float* s = src + ((size_t)b * CCH + c0) * NTOK + n0;
#pragma unroll
  for (int r = 0; r < 64; r += 4)
    tile[r + row4][col] = s[(size_t)(r + row4) * NTOK + col];
  __syncthreads();
  f16_t* d = dst + ((size_t)b * NTOK + n0) * CCH + c0;
#pragma unroll
  for (int r = 0; r < 64; r += 4)
    d[(size_t)(r + row4) * CCH + col] = (f16_t)tile[col][r + row4];
}

// -------- weight transpose: [O][I][27] f32 -> rows o_base+o of [27][Mtot][1024]
__global__ __launch_bounds__(256) void wtrans_kernel(
    const float* __restrict__ w, f16_t* __restrict__ wt, const int o_base,
    const int Mtot) {
  __shared__ float buf[64 * 27];
  const int o  = blockIdx.x;
  const int i0 = blockIdx.y * 64;
  const float* s = w + (size_t)o * (CCH * 27) + (size_t)i0 * 27;
  for (int idx = threadIdx.x; idx < 64 * 27; idx += 256) buf[idx] = s[idx];
  __syncthreads();
  for (int idx = threadIdx.x; idx < 64 * 27; idx += 256) {
    const int t = idx >> 6;
    const int i = idx & 63;
    wt[((size_t)t * Mtot + o_base + o) * 1024 + i0 + i] = (f16_t)buf[i * 27 + t];
  }
}

// ================= conv K+V fused: M=2048, tile 256x256, BK=64 (R6) ==========
__global__ __launch_bounds__(512, 2) void conv_kv_kernel(
    const f16_t* __restrict__ y_t, const f16_t* __restrict__ wkv,
    const float* __restrict__ bkv, f16_t* __restrict__ kb,
    f16_t* __restrict__ vb, const char* __restrict__ zp) {
  __shared__ char lds[131072];
  const int tid  = threadIdx.x;
  const int lane = tid & 63;
  const int wid  = tid >> 6;
  const int wr = wid >> 2, wc = wid & 3;   // 2M x 4N

  const int id = blockIdx.x;               // 256 blocks
  const int panel  = id & 7;               // 0..7 (0-3 = k, 4-7 = v)
  const int n_tile = id >> 3;              // 0..31
  const int m0  = panel * 256;             // row in 2048
  const int bn0 = n_tile * 256;
  const int b   = bn0 >> 9;
  const int n0  = bn0 & 511;
  const char* src_c = (const char*)y_t + (size_t)b * NTOK * 2048;
  const char* w_c   = (const char*)wkv;

  const int slotsrc16 = (((tid & 3) ^ ((tid >> 3) & 3)) << 4);
  const int t16 = tid << 4;
  const int r0t = tid >> 2;                // 0..127
  const size_t arow0 = (size_t)(m0 + r0t) * 2048 + slotsrc16;

  int cur_tap = -1;
  const char* bp0 = zp;
  const char* bp1 = zp;

  const int fr = lane & 15;
  const int rdbase = fr * 64 + (((lane >> 4) ^ ((fr >> 1) & 3)) << 4);

  f32x4 acc[8][4] = {};

  auto stage_half = [&](int tt, int kh, int reg) {
    const int te = (tt < NKT) ? tt : tt - 2;   // parity-preserving tail remap
    const int tap = te >> 4, kt = te & 15;
    if (tap != cur_tap) {
      cur_tap = tap;
      const int kd = tap / 9, rem = tap % 9, kh3 = rem / 3, kw3 = rem % 3;
#pragma unroll
      for (int l = 0; l < 2; ++l) {
        const int n = n0 + r0t + l * 128;
        const int d = (n >> 6) + kd - 1;
        const int h = ((n >> 3) & 7) + kh3 - 1;
        const int w = (n & 7) + kw3 - 1;
        const bool ok = ((unsigned)d < 8u) & ((unsigned)h < 8u) & ((unsigned)w < 8u);
        const int nsrc = (d << 6) + (h << 3) + w;
        const char* p = ok ? src_c + (size_t)nsrc * 2048 + slotsrc16 : zp;
        if (l == 0) bp0 = p; else bp1 = p;
      }
    }
    const size_t gA = (size_t)tap * (2048u * 2048u) + (size_t)(kt * 128 + kh * 64);
    char* La = lds + reg;
    gload_lds16(w_c + gA + arow0,                      La + t16);          // A rows 0-127
    gload_lds16(w_c + gA + arow0 + (size_t)128 * 2048, La + 8192 + t16);   // A rows 128-255
    const int ko = kt * 128 + kh * 64;
    gload_lds16(bp0 + ko, La + 16384 + t16);                               // B tok 0-127
    gload_lds16(bp1 + ko, La + 24576 + t16);                               // B tok 128-255
  };

#define MFMA32(AV, BV)                                                         \
  _Pragma("unroll") for (int i = 0; i < 8; ++i) {                              \
    _Pragma("unroll") for (int j = 0; j < 4; ++j)                              \
        acc[i][j] = __builtin_amdgcn_mfma_f32_16x16x32_f16(                    \
            AV[i], BV[j], acc[i][j], 0, 0, 0);                                 \
  }

  // prologue: halves (0,0)(0,1)(1,0); wait half0 (keep 8 in flight)
  stage_half(0, 0, 0);
  stage_half(0, 1, 32768);
  stage_half(1, 0, 65536);
  asm volatile("s_waitcnt vmcnt(8)\n\ts_barrier" ::: "memory");

#pragma unroll 1
  for (int t = 0; t < NKT; ++t) {
    const int rb = (t & 1) << 16;
    // ---- phase kh0
    {
      const char* sA = lds + rb + wr * 8192 + rdbase;
      const char* sB = lds + rb + 16384 + wc * 4096 + rdbase;
      f16x8 av[8], bv[4];
#pragma unroll
      for (int j = 0; j < 4; ++j) bv[j] = *(const f16x8*)(sB + j * 1024);
#pragma unroll
      for (int i = 0; i < 8; ++i) av[i] = *(const f16x8*)(sA + i * 1024);
      stage_half(t + 1, 1, (((t + 1) & 1) << 16) + 32768);
      __builtin_amdgcn_s_setprio(1);
      MFMA32(av, bv)
      __builtin_amdgcn_s_setprio(0);
      asm volatile("s_waitcnt vmcnt(8)\n\ts_barrier" ::: "memory");
    }
    // ---- phase kh1
    {
      const char* sA = lds + rb + 32768 + wr * 8192 + rdbase;
      const char* sB = lds + rb + 32768 + 16384 + wc * 4096 + rdbase;
      f16x8 av[8], bv[4];
#pragma unroll
      for (int j = 0; j < 4; ++j) bv[j] = *(const f16x8*)(sB + j * 1024);
#pragma unroll
      for (int i = 0; i < 8; ++i) av[i] = *(const f16x8*)(sA + i * 1024);
      stage_half(t + 2, 0, (t & 1) << 16);
      __builtin_amdgcn_s_setprio(1);
      MFMA32(av, bv)
      __builtin_amdgcn_s_setprio(0);
      asm volatile("s_waitcnt vmcnt(8)\n\ts_barrier" ::: "memory");
    }
  }
#undef MFMA32

  // epilogue: C col=lane&15 -> token, row=(lane>>4)*4+reg -> channel
  const int rq = (lane >> 4) << 2;
  const bool is_k = panel < 4;
#pragma unroll
  for (int i = 0; i < 8; ++i) {
    const int c = m0 + wr * 128 + i * 16 + rq;       // 0..2047
    const float4 bs = *(const float4*)&bkv[c];
    if (is_k) {
#pragma unroll
      for (int j = 0; j < 4; ++j) {
        const int n = n0 + wc * 64 + j * 16 + fr;
        f16x4 pk;
        pk[0] = (f16_t)(acc[i][j][0] + bs.x);
        pk[1] = (f16_t)(acc[i][j][1] + bs.y);
        pk[2] = (f16_t)(acc[i][j][2] + bs.z);
        pk[3] = (f16_t)(acc[i][j][3] + bs.w);
        *(f16x4*)(kb + ((size_t)(b * NTOK + n)) * CCH + c) = pk;
      }
    } else {
      const int cc = c - 1024;
      const float bbv[4] = {bs.x, bs.y, bs.z, bs.w};
#pragma unroll
      for (int reg = 0; reg < 4; ++reg) {
        f16_t* dst = vb + ((size_t)b * CCH + cc + reg) * NTOK;
#pragma unroll
        for (int j = 0; j < 4; ++j) {
          const int n = n0 + wc * 64 + j * 16 + fr;
          dst[n] = (f16_t)(acc[i][j][reg] + bbv[reg]);
        }
      }
    }
  }
}

// ================= conv Q: M=1024, tile 256x128, BK=64 (R6 verbatim) =========
__global__ __launch_bounds__(512, 2) void conv_q_kernel(
    const f16_t* __restrict__ x_t, const f16_t* __restrict__ wqt,
    const float* __restrict__ bq, f16_t* __restrict__ qb,
    const char* __restrict__ zp) {
  __shared__ char lds[98304];
  const int tid  = threadIdx.x;
  const int lane = tid & 63;
  const int wid  = tid >> 6;
  const int wr = wid >> 1, wc = wid & 1;   // 4M x 2N

  const int id = blockIdx.x;               // 256 blocks
  const int panel  = id & 3;               // 0..3
  const int n_tile = id >> 2;              // 0..63
  const int m0  = panel * 256;
  const int bn0 = n_tile * 128;
  const int b   = bn0 >> 9;
  const int n0  = bn0 & 511;
  const char* src_c = (const char*)x_t + (size_t)b * NTOK * 2048;
  const char* w_c   = (const char*)wqt;

  const int slotsrc16 = (((tid & 3) ^ ((tid >> 3) & 3)) << 4);
  const int t16 = tid << 4;
  const int r0  = tid >> 2;
  const size_t arow0 = (size_t)(m0 + r0) * 2048 + slotsrc16;

  int cur_tap = -1;
  const char* bp0 = zp;

  const int fr = lane & 15;
  const int rdbase = fr * 64 + (((lane >> 4) ^ ((fr >> 1) & 3)) << 4);

  f32x4 acc[4][4] = {};

  auto upd_tap = [&](int tap) {
    cur_tap = tap;
    const int kd = tap / 9, rem = tap % 9, kh = rem / 3, kw = rem % 3;
    const int n = n0 + r0;
    const int d = (n >> 6) + kd - 1;
    const int h = ((n >> 3) & 7) + kh - 1;
    const int w = (n & 7) + kw - 1;
    const bool ok = ((unsigned)d < 8u) & ((unsigned)h < 8u) & ((unsigned)w < 8u);
    const int nsrc = (d << 6) + (h << 3) + w;
    bp0 = ok ? src_c + (size_t)nsrc * 2048 + slotsrc16 : zp;
  };
  auto stage_half = [&](int tt, int kh, int reg) {  // 3 loads
    const int te = (tt < NKT) ? tt : tt - 2;
    const int tap = te >> 4, kt = te & 15;
    if (tap != cur_tap) upd_tap(tap);
    const size_t gA = (size_t)tap * (1024u * 2048u) + (size_t)(kt * 128 + kh * 64);
    char* La = lds + reg;
    gload_lds16(w_c + gA + arow0,                      La + t16);
    gload_lds16(w_c + gA + arow0 + (size_t)128 * 2048, La + 8192 + t16);
    gload_lds16(bp0 + kt * 128 + kh * 64,              La + 16384 + t16);
  };

#define MFMA16Q(AV, BV)                                                        \
  _Pragma("unroll") for (int i = 0; i < 4; ++i) {                              \
    _Pragma("unroll") for (int j = 0; j < 4; ++j)                              \
        acc[i][j] = __builtin_amdgcn_mfma_f32_16x16x32_f16(                    \
            AV[i], BV[j], acc[i][j], 0, 0, 0);                                 \
  }

  stage_half(0, 0, 0);
  stage_half(0, 1, 24576);
  stage_half(1, 0, 49152);
  asm volatile("s_waitcnt vmcnt(6)\n\ts_barrier" ::: "memory");

#pragma unroll 1
  for (int t = 0; t < NKT; ++t) {
    const int rb = (t & 1) * 49152;               // region: tile t, kh0
    {
      const char* sA = lds + rb + wr * 4096 + rdbase;
      const char* sB = lds + rb + 16384 + wc * 4096 + rdbase;
      f16x8 av[4], bv[4];
#pragma unroll
      for (int j = 0; j < 4; ++j) bv[j] = *(const f16x8*)(sB + j * 1024);
#pragma unroll
      for (int i = 0; i < 4; ++i) av[i] = *(const f16x8*)(sA + i * 1024);
      stage_half(t + 1, 1, ((t + 1) & 1) * 49152 + 24576);
      __builtin_amdgcn_s_setprio(1);
      MFMA16Q(av, bv)
      __builtin_amdgcn_s_setprio(0);
      asm volatile("s_waitcnt vmcnt(6)\n\ts_barrier" ::: "memory");
    }
    {
      const char* sA = lds + rb + 24576 + wr * 4096 + rdbase;
      const char* sB = lds + rb + 24576 + 16384 + wc * 4096 + rdbase;
      f16x8 av[4], bv[4];
#pragma unroll
      for (int j = 0; j < 4; ++j) bv[j] = *(const f16x8*)(sB + j * 1024);
#pragma unroll
      for (int i = 0; i < 4; ++i) av[i] = *(const f16x8*)(sA + i * 1024);
      stage_half(t + 2, 0, (t & 1) * 49152);
      __builtin_amdgcn_s_setprio(1);
      MFMA16Q(av, bv)
      __builtin_amdgcn_s_setprio(0);
      asm volatile("s_waitcnt vmcnt(6)\n\ts_barrier" ::: "memory");
    }
  }
#undef MFMA16Q

  const int rq = (lane >> 4) << 2;
#pragma unroll
  for (int i = 0; i < 4; ++i) {
    const int c = m0 + wr * 64 + i * 16 + rq;        // 0..1023
    const float4 bs = *(const float4*)&bq[c];
#pragma unroll
    for (int j = 0; j < 4; ++j) {
      const int n = n0 + wc * 64 + j * 16 + fr;
      f16x4 pk;
      pk[0] = (f16_t)(acc[i][j][0] + bs.x);
      pk[1] = (f16_t)(acc[i][j][1] + bs.y);
      pk[2] = (f16_t)(acc[i][j][2] + bs.z);
      pk[3] = (f16_t)(acc[i][j][3] + bs.w);
      *(f16x4*)(qb + ((size_t)(b * NTOK + n)) * CCH + c) = pk;
    }
  }
}

// ========== fused scores+softmax: P[b][n][m] = softmax_m(q[b][n]·k[b][m]) ====
// 64 blocks (4 row-tiles x 16 batches), 512 thr = 8 waves (2M x 4N),
// wave tile 64 rows x 128 keys, acc 4x8. K=1024 = 16 tiles of 64.
// Single-buffer LDS (A 16K + B 64K), syncthreads both sides (small kernel).
// Softmax: per-lane j-reduce -> shfl_xor over 16-lane col group -> cross-wave
// combine via smax/ssum[128][4] in LDS -> write P f16 directly.
__global__ __launch_bounds__(512) void qk_softmax_kernel(
    const f16_t* __restrict__ qb, const f16_t* __restrict__ kb,
    f16_t* __restrict__ P) {
  __shared__ char lds[86016];
  f16_t* As = (f16_t*)lds;              // [128][64]
  f16_t* Bs = (f16_t*)(lds + 16384);    // [512][64]
  float* smax = (float*)(lds + 81920);  // [128][4]
  float* ssum = (float*)(lds + 83968);  // [128][4]

  const int tid  = threadIdx.x;
  const int lane = tid & 63;
  const int wid  = tid >> 6;
  const int wr = wid >> 2, wc = wid & 3;   // 2 row-groups x 4 col-groups
  const int b  = blockIdx.y;
  const int n0 = blockIdx.x * 128;

  const int fr = lane & 15;
  const int fk = (lane >> 4) << 3;

  const char* ap[2];
  const char* bp[8];
#pragma unroll
  for (int r = 0; r < 2; ++r)
    ap[r] = (const char*)(qb + ((size_t)b * NTOK + n0 + r * 64 + (tid >> 3)) * CCH) + (tid & 7) * 16;
#pragma unroll
  for (int r = 0; r < 8; ++r)
    bp[r] = (const char*)(kb + ((size_t)b * NTOK + r * 64 + (tid >> 3)) * CCH) + (tid & 7) * 16;

  f32x4 acc[4][8] = {};

  for (int k0 = 0; k0 < 16; ++k0) {
#pragma unroll
    for (int r = 0; r < 2; ++r) gload_lds16(ap[r], (char*)As + r * 8192 + tid * 16);
#pragma unroll
    for (int r = 0; r < 8; ++r) gload_lds16(bp[r], (char*)Bs + r * 8192 + tid * 16);
#pragma unroll
    for (int r = 0; r < 2; ++r) ap[r] += 128;
#pragma unroll
    for (int r = 0; r < 8; ++r) bp[r] += 128;
    __syncthreads();
#pragma unroll
    for (int ks = 0; ks < 2; ++ks) {
      const int kc = ks * 32 + fk;
      f16x8 av[4], bv[8];
#pragma unroll
      for (int i = 0; i < 4; ++i)
        av[i] = *(const f16x8*)&As[(wr * 64 + i * 16 + fr) * 64 + kc];
#pragma unroll
      for (int j = 0; j < 8; ++j)
        bv[j] = *(const f16x8*)&Bs[(wc * 128 + j * 16 + fr) * 64 + kc];
#pragma unroll
      for (int i = 0; i < 4; ++i)
#pragma unroll
        for (int j = 0; j < 8; ++j)
          acc[i][j] = __builtin_amdgcn_mfma_f32_16x16x32_f16(av[i], bv[j], acc[i][j], 0, 0, 0);
    }
    __syncthreads();
  }

  // ---- softmax over 512 keys per row; row = wr*64 + i*16 + (lane>>4)*4 + r
  const int rbase = wr * 64 + ((lane >> 4) << 2);
  float mx[4][4];
#pragma unroll
  for (int i = 0; i < 4; ++i)
#pragma unroll
    for (int r = 0; r < 4; ++r) {
      float v = acc[i][0][r];
#pragma unroll
      for (int j = 1; j < 8; ++j) v = fmaxf(v, acc[i][j][r]);
#pragma unroll
      for (int o = 1; o <= 8; o <<= 1) v = fmaxf(v, __shfl_xor(v, o, 64));
      mx[i][r] = v;
    }
  if (fr == 0) {
#pragma unroll
    for (int i = 0; i < 4; ++i)
#pragma unroll
      for (int r = 0; r < 4; ++r)
        smax[(rbase + i * 16 + r) * 4 + wc] = mx[i][r];
  }
  __syncthreads();
#pragma unroll
  for (int i = 0; i < 4; ++i)
#pragma unroll
    for (int r = 0; r < 4; ++r) {
      const int row = rbase + i * 16 + r;
      mx[i][r] = fmaxf(fmaxf(smax[row * 4 + 0], smax[row * 4 + 1]),
                       fmaxf(smax[row * 4 + 2], smax[row * 4 + 3]));
    }
  float sm[4][4];
#pragma unroll
  for (int i = 0; i < 4; ++i)
#pragma unroll
    for (int r = 0; r < 4; ++r) {
      float s = 0.f;
#pragma unroll
      for (int j = 0; j < 8; ++j) {
        acc[i][j][r] = __expf(acc[i][j][r] - mx[i][r]);
        s += acc[i][j][r];
      }
#pragma unroll
      for (int o = 1; o <= 8; o <<= 1) s += __shfl_xor(s, o, 64);
      sm[i][r] = s;
    }
  if (fr == 0) {
#pragma unroll
    for (int i = 0; i < 4; ++i)
#pragma unroll
      for (int r = 0; r < 4; ++r)
        ssum[(rbase + i * 16 + r) * 4 + wc] = sm[i][r];
  }
  __syncthreads();
  f16_t* Pb = P + (size_t)b * NTOK * NTOK;
#pragma unroll
  for (int i = 0; i < 4; ++i)
#pragma unroll
    for (int r = 0; r < 4; ++r) {
      const int row = rbase + i * 16 + r;
      const float tot = (ssum[row * 4 + 0] + ssum[row * 4 + 1]) +
                        (ssum[row * 4 + 2] + ssum[row * 4 + 3]);
      const float rinv = 1.0f / tot;
      f16_t* prow = Pb + (size_t)(n0 + row) * NTOK + wc * 128 + fr;
#pragma unroll
      for (int j = 0; j < 8; ++j)
        prow[j * 16] = (f16_t)(acc[i][j][r] * rinv);
    }
}

// ---------------- generic gemm_bt for attention PV: C = A * Bt^T (+resid) ----
__global__ __launch_bounds__(256) void attn_gemm_kernel(
    const f16_t* __restrict__ A, const f16_t* __restrict__ Bt,
    float* __restrict__ Cout, const float* __restrict__ resid,
    const int Kdim, const int ldc,
    const size_t strideA, const size_t strideB, const size_t strideC) {
  __shared__ f16_t As[128 * 64];
  __shared__ f16_t Bs[128 * 64];
  char* As_c = (char*)As;
  char* Bs_c = (char*)Bs;

  const int tid  = threadIdx.x;
  const int lane = tid & 63;
  const int wave = tid >> 6;
  const int wr = wave >> 1, wc = wave & 1;
  const int bz = blockIdx.z;
  const int m0 = blockIdx.y * 128;
  const int n0 = blockIdx.x * 128;

  const f16_t* Ab = A + (size_t)bz * strideA;
  const f16_t* Bb = Bt + (size_t)bz * strideB;

  const int rowb = tid >> 3;
  const int colb = (tid & 7) * 16;

  const char* ap[4];
  const char* bp[4];
#pragma unroll
  for (int r = 0; r < 4; ++r) {
    const int row = r * 32 + rowb;
    ap[r] = (const char*)(Ab + (size_t)(m0 + row) * Kdim) + colb;
    bp[r] = (const char*)(Bb + (size_t)(n0 + row) * Kdim) + colb;
  }

  f32x4 acc[4][4] = {};
  const int fr = lane & 15;
  const int fk = (lane >> 4) << 3;

  for (int k0 = 0; k0 < Kdim; k0 += 64) {
#pragma unroll
    for (int r = 0; r < 4; ++r)
      gload_lds16(ap[r], As_c + r * 4096 + wave * 1024);
#pragma unroll
    for (int r = 0; r < 4; ++r)
      gload_lds16(bp[r], Bs_c + r * 4096 + wave * 1024);
#pragma unroll
    for (int r = 0; r < 4; ++r) { ap[r] += 128; bp[r] += 128; }
    __syncthreads();
#pragma unroll
    for (int ks = 0; ks < 2; ++ks) {
      const int kc = ks * 32 + fk;
      f16x8 av[4], bv[4];
#pragma unroll
      for (int i = 0; i < 4; ++i)
        av[i] = *(const f16x8*)&As[(wr * 64 + i * 16 + fr) * 64 + kc];
#pragma unroll
      for (int i = 0; i < 4; ++i)
        bv[i] = *(const f16x8*)&Bs[(wc * 64 + i * 16 + fr) * 64 + kc];
#pragma unroll
      for (int i = 0; i < 4; ++i)
#pragma unroll
        for (int j = 0; j < 4; ++j)
          acc[i][j] = __builtin_amdgcn_mfma_f32_16x16x32_f16(av[i], bv[j], acc[i][j], 0, 0, 0);
    }
    __syncthreads();
  }

  const int mo = m0 + wr * 64 + ((lane >> 4) << 2);
  const int nn = n0 + wc * 64 + (lane & 15);
  float* Cb = Cout + (size_t)bz * strideC;
  const float* Rb = resid ? resid + (size_t)bz * strideC : nullptr;
#pragma unroll
  for (int i = 0; i < 4; ++i) {
#pragma unroll
    for (int j = 0; j < 4; ++j) {
      const int n = nn + j * 16;
#pragma unroll
      for (int reg = 0; reg < 4; ++reg) {
        const int m = mo + i * 16 + reg;
        float v = acc[i][j][reg];
        if (Rb) v += Rb[(size_t)m * ldc + n];
        Cb[(size_t)m * ldc + n] = v;
      }
    }
  }
}

// -----------------------------------------------------------------------------
extern "C" void kernel_launch(void* const* d_in, const int* in_sizes, int n_in,
                              void* d_out, int out_size, void* d_ws, size_t ws_size,
                              hipStream_t stream) {
  (void)in_sizes; (void)n_in; (void)out_size;
  const float* x  = (const float*)d_in[0];
  const float* y  = (const float*)d_in[1];
  const float* wq = (const float*)d_in[2];
  const float* bq = (const float*)d_in[3];
  const float* wk = (const float*)d_in[4];
  const float* bk = (const float*)d_in[5];
  const float* wv = (const float*)d_in[6];
  const float* bv = (const float*)d_in[7];

  char* ws = (char*)d_ws;
  size_t off = 0;
  auto alloc = [&](size_t bytes) {
    void* p = ws + off;
    off = (off + bytes + 255) & ~(size_t)255;
    return p;
  };
  const size_t act_b = (size_t)BATCH * NTOK * CCH * 2;  // 16 MB
  f16_t* x_t    = (f16_t*)alloc(act_b);
  f16_t* y_t    = (f16_t*)alloc(act_b);
  f16_t* wkv    = (f16_t*)alloc((size_t)27 * 2048 * 1024 * 2);   // 113 MB
  f16_t* wqt    = (f16_t*)alloc((size_t)27 * 1024 * 1024 * 2);   //  57 MB
  float* bkv    = (float*)alloc(2048 * 4);
  f16_t* qb     = (f16_t*)alloc(act_b);
  f16_t* kb     = (f16_t*)alloc(act_b);
  f16_t* vb     = (f16_t*)alloc(act_b);
  f16_t* Pb     = (f16_t*)alloc((size_t)BATCH * 512 * 512 * 2);  //  8 MB
  char*  zerop  = (char*)alloc(4096);
  if (off > ws_size) return;

  const dim3 blk(256);
  hipMemsetAsync(zerop, 0, 4096, stream);
  cast_transpose_kernel<<<dim3(8, 16, 16), blk, 0, stream>>>(x, x_t);
  cast_transpose_kernel<<<dim3(8, 16, 16), blk, 0, stream>>>(y, y_t);

  wtrans_kernel<<<dim3(1024, 16), blk, 0, stream>>>(wk, wkv, 0, 2048);
  wtrans_kernel<<<dim3(1024, 16), blk, 0, stream>>>(wv, wkv, 1024, 2048);
  wtrans_kernel<<<dim3(1024, 16), blk, 0, stream>>>(wq, wqt, 0, 1024);
  hipMemcpyAsync(bkv,        bk, 1024 * 4, hipMemcpyDeviceToDevice, stream);
  hipMemcpyAsync(bkv + 1024, bv, 1024 * 4, hipMemcpyDeviceToDevice, stream);

  conv_kv_kernel<<<dim3(256), dim3(512), 0, stream>>>(y_t, wkv, bkv, kb, vb, zerop);
  conv_q_kernel<<<dim3(256), dim3(512), 0, stream>>>(x_t, wqt, bq, qb, zerop);

  // P[b][n][m] = softmax_m( q[b][n]·k[b][m] )  (fused, writes f16 directly)
  qk_softmax_kernel<<<dim3(4, 16), dim3(512), 0, stream>>>(qb, kb, Pb);
  // out[b][c][n] = sum_m v[b][c][m] * P[b][n][m] + x[b][c][n]
  attn_gemm_kernel<<<dim3(4, 8, 16), blk, 0, stream>>>(
      vb, Pb, (float*)d_out, x, 512, 512,
      (size_t)1024 * 512, (size_t)512 * 512, (size_t)1024 * 512);
}